// Round 8
// baseline (300.489 us; speedup 1.0000x reference)
//
#include <hip/hip_runtime.h>

#define D 96          // feature dim
#define D4 24         // float4s per row
#define XSTR 100      // Xs row stride in floats
#define TROW 4        // uint4 per sub-table row (64B, last 16B pad)
typedef unsigned int uint;
typedef unsigned short ushort;

// ---------- bf16 helpers (RNE) ----------
__device__ __forceinline__ ushort f2bf(float f) {
    uint u = __float_as_uint(f);
    u = (u + 0x7FFFu + ((u >> 16) & 1u)) >> 16;
    return (ushort)u;
}
__device__ __forceinline__ uint pack2(float a, float b) {
    return (uint)f2bf(a) | ((uint)f2bf(b) << 16);
}
__device__ __forceinline__ void add8(float* a, uint4 c) {
    a[0] += __uint_as_float(c.x << 16);
    a[1] += __uint_as_float(c.x & 0xFFFF0000u);
    a[2] += __uint_as_float(c.y << 16);
    a[3] += __uint_as_float(c.y & 0xFFFF0000u);
    a[4] += __uint_as_float(c.z << 16);
    a[5] += __uint_as_float(c.z & 0xFFFF0000u);
    a[6] += __uint_as_float(c.w << 16);
    a[7] += __uint_as_float(c.w & 0xFFFF0000u);
}
__device__ __forceinline__ void set8s(float* a, uint4 c, float s) {
    a[0] = s * __uint_as_float(c.x << 16);
    a[1] = s * __uint_as_float(c.x & 0xFFFF0000u);
    a[2] = s * __uint_as_float(c.y << 16);
    a[3] = s * __uint_as_float(c.y & 0xFFFF0000u);
    a[4] = s * __uint_as_float(c.z << 16);
    a[5] = s * __uint_as_float(c.z & 0xFFFF0000u);
    a[6] = s * __uint_as_float(c.w << 16);
    a[7] = s * __uint_as_float(c.w & 0xFFFF0000u);
}

// feat fp32 [N][96] -> 4 sub-tables T0[g][N][TROW] uint4 (cols 24g..24g+23, 48B + 16B pad)
__global__ void to_bf16_4g(const float4* __restrict__ X4, uint4* __restrict__ T0, int N) {
    int t = blockIdx.x * blockDim.x + threadIdx.x;
    if (t >= N * 4) return;
    int v = t >> 2, g = t & 3;
    const float4* s = X4 + (size_t)v * D4 + g * 6;
    uint4* d = T0 + ((size_t)g * N + v) * TROW;
    float4 f0 = s[0], f1 = s[1], f2 = s[2], f3 = s[3], f4 = s[4], f5 = s[5];
    d[0] = make_uint4(pack2(f0.x,f0.y), pack2(f0.z,f0.w), pack2(f1.x,f1.y), pack2(f1.z,f1.w));
    d[1] = make_uint4(pack2(f2.x,f2.y), pack2(f2.z,f2.w), pack2(f3.x,f3.y), pack2(f3.z,f3.w));
    d[2] = make_uint4(pack2(f4.x,f4.y), pack2(f4.z,f4.w), pack2(f5.x,f5.y), pack2(f5.z,f5.w));
}

// ======================= CSR build =======================

__global__ void hist_kernel(const int* __restrict__ dst, int* __restrict__ deg, int E) {
    int e = blockIdx.x * blockDim.x + threadIdx.x;
    if (e < E) atomicAdd(&deg[dst[e]], 1);
}

__global__ void block_sums(const int* __restrict__ deg, int* __restrict__ bsums, int N) {
    __shared__ int s[256];
    int t = threadIdx.x;
    int base = blockIdx.x * 1024 + t * 4;
    int sum = 0;
#pragma unroll
    for (int j = 0; j < 4; ++j) { int i = base + j; if (i < N) sum += deg[i]; }
    s[t] = sum; __syncthreads();
    for (int off = 128; off > 0; off >>= 1) {
        if (t < off) s[t] += s[t + off];
        __syncthreads();
    }
    if (t == 0) bsums[blockIdx.x] = s[0];
}

__global__ void scan_small(const int* __restrict__ bsums, int* __restrict__ boff,
                           int* __restrict__ total_out, int nb) {
    if (threadIdx.x == 0 && blockIdx.x == 0) {
        int acc = 0;
        for (int i = 0; i < nb; ++i) { boff[i] = acc; acc += bsums[i]; }
        *total_out = acc;
    }
}

__global__ void scan_write(const int* __restrict__ deg, const int* __restrict__ boff,
                           int* __restrict__ rowptr, int N) {
    __shared__ int s[256];
    int t = threadIdx.x;
    int base = blockIdx.x * 1024 + t * 4;
    int v[4]; int tsum = 0;
#pragma unroll
    for (int j = 0; j < 4; ++j) { int i = base + j; v[j] = (i < N) ? deg[i] : 0; tsum += v[j]; }
    s[t] = tsum; __syncthreads();
    for (int off = 1; off < 256; off <<= 1) {
        int x = (t >= off) ? s[t - off] : 0;
        __syncthreads();
        s[t] += x;
        __syncthreads();
    }
    int excl = s[t] - tsum + boff[blockIdx.x];
#pragma unroll
    for (int j = 0; j < 4; ++j) { int i = base + j; if (i < N) rowptr[i] = excl; excl += v[j]; }
}

__global__ void fill_edges(const int* __restrict__ src, const int* __restrict__ dst,
                           int* __restrict__ cursor, int* __restrict__ esrc, int E) {
    int e = blockIdx.x * blockDim.x + threadIdx.x;
    if (e >= E) return;
    int pos = atomicAdd(&cursor[dst[e]], 1);
    esrc[pos] = src[e];
}

// ======================= gather, XCD-sliced =======================
// Column-group g = (blockIdx%8)>>1 -> 2 XCDs per group (blockIdx%8 ~ XCD).
// Each XCD randomly reads ONLY its 3.2MB sub-table -> L2-resident.
// 1 thread per node: self (bf16) + sum of neighbors; agg layout [4][N][24] fp32.
__global__ __launch_bounds__(256) void gather4(
    const uint4* __restrict__ T0, const int* __restrict__ rowptr,
    const int* __restrict__ esrc, const float* __restrict__ eps_p,
    float4* __restrict__ agg4, int N) {
    int b = blockIdx.x;
    int x = b & 7, g = x >> 1;
    int nb = ((b >> 3) << 1) | (x & 1);
    int v = nb * 256 + threadIdx.x;
    if (v >= N) return;
    const uint4* T = T0 + (size_t)g * N * TROW;
    float a[24];
    {
        const uint4* rp = T + (size_t)v * TROW;
        uint4 c0 = rp[0], c1 = rp[1], c2 = rp[2];
        float s = 1.0f + eps_p[0];
        set8s(a + 0, c0, s); set8s(a + 8, c1, s); set8s(a + 16, c2, s);
    }
    int e = rowptr[v], e1 = rowptr[v + 1];
    for (; e + 1 < e1; e += 2) {
        const uint4* r0 = T + (size_t)esrc[e] * TROW;
        const uint4* r1 = T + (size_t)esrc[e + 1] * TROW;
        uint4 c00 = r0[0], c01 = r0[1], c02 = r0[2];
        uint4 c10 = r1[0], c11 = r1[1], c12 = r1[2];
        add8(a + 0, c00); add8(a + 8, c01); add8(a + 16, c02);
        add8(a + 0, c10); add8(a + 8, c11); add8(a + 16, c12);
    }
    if (e < e1) {
        const uint4* r0 = T + (size_t)esrc[e] * TROW;
        add8(a + 0, r0[0]); add8(a + 8, r0[1]); add8(a + 16, r0[2]);
    }
    float4* dst = agg4 + ((size_t)g * N + v) * 6;
#pragma unroll
    for (int i = 0; i < 6; ++i)
        dst[i] = make_float4(a[4*i], a[4*i+1], a[4*i+2], a[4*i+3]);
}

// ======================= MLP (2x GEMM+ReLU) =======================
// 64 rows/block, 256 threads. Stage agg[4][N][24] -> Xs rows; wave-uniform W
// (scalar loads); outputs: fp32 Y (optional) and/or bf16 sub-tables Yb (optional).
__global__ __launch_bounds__(256) void mlp96(
    const float4* __restrict__ agg4,
    const float* __restrict__ Wa, const float* __restrict__ ba,
    const float* __restrict__ Wb, const float* __restrict__ bb,
    float* __restrict__ Y, uint4* __restrict__ Yb, int N) {
    __shared__ float Xs[64 * XSTR];
    int tid = threadIdx.x;
    int R0 = blockIdx.x * 64;

    // stage: 4 contiguous [64][24] fp32 regions -> Xs columns
#pragma unroll
    for (int i = 0; i < 6; ++i) {
        int idx = tid + i * 256;           // 0..1535
        int g = idx / 384;
        int j = idx - g * 384;
        int row = j / 6, c4 = j - row * 6;
        float4 val = make_float4(0.f, 0.f, 0.f, 0.f);
        if (R0 + row < N) val = agg4[((size_t)g * N + R0 + row) * 6 + c4];
        *(float4*)&Xs[row * XSTR + g * 24 + c4 * 4] = val;
    }
    __syncthreads();

    int lane = tid & 63;
    int c0 = __builtin_amdgcn_readfirstlane(tid >> 6) * 24;

    float acc[24];
#pragma unroll
    for (int j = 0; j < 24; ++j) acc[j] = ba[c0 + j];
#pragma unroll 2
    for (int k0 = 0; k0 < D; k0 += 4) {
        float4 xv = *(const float4*)&Xs[lane * XSTR + k0];
        const float* xf = (const float*)&xv;
#pragma unroll
        for (int kk = 0; kk < 4; ++kk) {
            float xx = xf[kk];
            const float* wr = &Wa[(k0 + kk) * D + c0];
#pragma unroll
            for (int j = 0; j < 24; ++j) acc[j] = fmaf(xx, wr[j], acc[j]);
        }
    }
    __syncthreads();

#pragma unroll
    for (int j = 0; j < 24; j += 4) {
        float4 h = make_float4(fmaxf(acc[j+0],0.f), fmaxf(acc[j+1],0.f),
                               fmaxf(acc[j+2],0.f), fmaxf(acc[j+3],0.f));
        *(float4*)&Xs[lane * XSTR + c0 + j] = h;
    }
    __syncthreads();

    float acc2[24];
#pragma unroll
    for (int j = 0; j < 24; ++j) acc2[j] = bb[c0 + j];
#pragma unroll 2
    for (int k0 = 0; k0 < D; k0 += 4) {
        float4 xv = *(const float4*)&Xs[lane * XSTR + k0];
        const float* xf = (const float*)&xv;
#pragma unroll
        for (int kk = 0; kk < 4; ++kk) {
            float xx = xf[kk];
            const float* wr = &Wb[(k0 + kk) * D + c0];
#pragma unroll
            for (int j = 0; j < 24; ++j) acc2[j] = fmaf(xx, wr[j], acc2[j]);
        }
    }
    __syncthreads();

#pragma unroll
    for (int j = 0; j < 24; j += 4) {
        float4 o = make_float4(fmaxf(acc2[j+0],0.f), fmaxf(acc2[j+1],0.f),
                               fmaxf(acc2[j+2],0.f), fmaxf(acc2[j+3],0.f));
        *(float4*)&Xs[lane * XSTR + c0 + j] = o;
    }
    __syncthreads();

    if (Y) {
        int r = tid >> 2, q = tid & 3;
        int v = R0 + r;
        if (v < N) {
            float4* Y4 = (float4*)Y;
#pragma unroll
            for (int k = 0; k < 6; ++k)
                Y4[v * D4 + k * 4 + q] = *(const float4*)&Xs[r * XSTR + (k * 4 + q) * 4];
        }
    }
    if (Yb) {
#pragma unroll
        for (int k = 0; k < 3; ++k) {
            int c = tid + 256 * k;          // 0..767 = 64 rows x 4 groups x 3 parts
            int row = c / 12, rem = c - row * 12;
            int g = rem / 3, part = rem - g * 3;
            int v = R0 + row;
            if (v < N) {
                const float* p = &Xs[row * XSTR + g * 24 + part * 8];
                float4 f0 = *(const float4*)p;
                float4 f1 = *(const float4*)(p + 4);
                Yb[((size_t)g * N + v) * TROW + part] =
                    make_uint4(pack2(f0.x,f0.y), pack2(f0.z,f0.w),
                               pack2(f1.x,f1.y), pack2(f1.z,f1.w));
            }
        }
    }
}

// ======================= tier-2 fallback: fused fp32 layer (R6 <false>) =======================
__global__ __launch_bounds__(256) void gin_layer_f32(
    const float* __restrict__ X, const int* __restrict__ rowptr,
    const int* __restrict__ esrc, const float* __restrict__ eps_p,
    const float* __restrict__ Wa, const float* __restrict__ ba,
    const float* __restrict__ Wb, const float* __restrict__ bb,
    float* __restrict__ Y, int N) {
    __shared__ float Xs[64 * XSTR];
    int tid = threadIdx.x;
    int R0 = blockIdx.x * 64;
    {
        int r = tid >> 2, q = tid & 3;
        int v = R0 + r;
        float a[24];
        if (v < N) {
            const float4* X4 = (const float4*)X;
            float s = 1.0f + eps_p[0];
#pragma unroll
            for (int i = 0; i < 6; ++i) {
                float4 xv = X4[v * D4 + 6 * q + i];
                a[4*i+0]=s*xv.x; a[4*i+1]=s*xv.y; a[4*i+2]=s*xv.z; a[4*i+3]=s*xv.w;
            }
            int e = rowptr[v], e1 = rowptr[v + 1];
            for (; e < e1; ++e) {
                int u = esrc[e] * D4 + 6 * q;
#pragma unroll
                for (int i = 0; i < 6; ++i) {
                    float4 m = X4[u + i];
                    a[4*i+0]+=m.x; a[4*i+1]+=m.y; a[4*i+2]+=m.z; a[4*i+3]+=m.w;
                }
            }
        } else {
#pragma unroll
            for (int j = 0; j < 24; ++j) a[j] = 0.f;
        }
#pragma unroll
        for (int i = 0; i < 6; ++i)
            *(float4*)&Xs[r * XSTR + q * 24 + 4 * i] =
                make_float4(a[4*i], a[4*i+1], a[4*i+2], a[4*i+3]);
    }
    __syncthreads();
    int lane = tid & 63;
    int c0 = __builtin_amdgcn_readfirstlane(tid >> 6) * 24;
    float acc[24];
#pragma unroll
    for (int j = 0; j < 24; ++j) acc[j] = ba[c0 + j];
#pragma unroll 2
    for (int k0 = 0; k0 < D; k0 += 4) {
        float4 xv = *(const float4*)&Xs[lane * XSTR + k0];
        const float* xf = (const float*)&xv;
#pragma unroll
        for (int kk = 0; kk < 4; ++kk) {
            float xx = xf[kk];
            const float* wr = &Wa[(k0 + kk) * D + c0];
#pragma unroll
            for (int j = 0; j < 24; ++j) acc[j] = fmaf(xx, wr[j], acc[j]);
        }
    }
    __syncthreads();
#pragma unroll
    for (int j = 0; j < 24; j += 4) {
        float4 h = make_float4(fmaxf(acc[j+0],0.f), fmaxf(acc[j+1],0.f),
                               fmaxf(acc[j+2],0.f), fmaxf(acc[j+3],0.f));
        *(float4*)&Xs[lane * XSTR + c0 + j] = h;
    }
    __syncthreads();
    float acc2[24];
#pragma unroll
    for (int j = 0; j < 24; ++j) acc2[j] = bb[c0 + j];
#pragma unroll 2
    for (int k0 = 0; k0 < D; k0 += 4) {
        float4 xv = *(const float4*)&Xs[lane * XSTR + k0];
        const float* xf = (const float*)&xv;
#pragma unroll
        for (int kk = 0; kk < 4; ++kk) {
            float xx = xf[kk];
            const float* wr = &Wb[(k0 + kk) * D + c0];
#pragma unroll
            for (int j = 0; j < 24; ++j) acc2[j] = fmaf(xx, wr[j], acc2[j]);
        }
    }
    __syncthreads();
#pragma unroll
    for (int j = 0; j < 24; j += 4) {
        float4 o = make_float4(fmaxf(acc2[j+0],0.f), fmaxf(acc2[j+1],0.f),
                               fmaxf(acc2[j+2],0.f), fmaxf(acc2[j+3],0.f));
        *(float4*)&Xs[lane * XSTR + c0 + j] = o;
    }
    __syncthreads();
    {
        int r = tid >> 2, q = tid & 3;
        int v = R0 + r;
        if (v < N) {
            float4* Y4 = (float4*)Y;
#pragma unroll
            for (int k = 0; k < 6; ++k)
                Y4[v * D4 + k * 4 + q] = *(const float4*)&Xs[r * XSTR + (k * 4 + q) * 4];
        }
    }
}

// ======================= launch =======================

extern "C" void kernel_launch(void* const* d_in, const int* in_sizes, int n_in,
                              void* d_out, int out_size, void* d_ws, size_t ws_size,
                              hipStream_t stream) {
    const float* feat = (const float*)d_in[0];
    const int*   src  = (const int*)d_in[1];
    const int*   dst  = (const int*)d_in[2];
    const float* eps1 = (const float*)d_in[3];
    const float* W1a  = (const float*)d_in[4];
    const float* b1a  = (const float*)d_in[5];
    const float* W1b  = (const float*)d_in[6];
    const float* b1b  = (const float*)d_in[7];
    const float* eps2 = (const float*)d_in[8];
    const float* W2a  = (const float*)d_in[9];
    const float* b2a  = (const float*)d_in[10];
    const float* W2b  = (const float*)d_in[11];
    const float* b2b  = (const float*)d_in[12];

    int N = in_sizes[0] / D;     // 50000
    int E = in_sizes[1];         // 800000

    float* out = (float*)d_out;

    char* w = (char*)d_ws;
    size_t off = 0;
    auto carve = [&](size_t bytes) -> void* {
        void* p = w + off;
        off += (bytes + 255) & ~(size_t)255;
        return p;
    };
    int*   rowptr = (int*)carve((size_t)(N + 1) * sizeof(int));
    int*   deg    = (int*)carve((size_t)N * sizeof(int));
    int*   cursor = (int*)carve((size_t)N * sizeof(int));
    int*   esrc   = (int*)carve((size_t)E * sizeof(int));
    int nb = (N + 1023) / 1024;
    int*   bsums  = (int*)carve((size_t)nb * sizeof(int));
    int*   boff   = (int*)carve((size_t)nb * sizeof(int));
    bool csr_ok = (off <= ws_size);
    size_t base = off;
    uint4* tab4 = (uint4*)carve((size_t)4 * N * TROW * sizeof(uint4));  // 12.8 MB (shared L1-in/L1-out)
    float* agg  = (float*)carve((size_t)4 * N * 24 * sizeof(float));    // 19.2 MB
    bool full_ok = (off <= ws_size);
    float* A = (float*)(w + base);                                      // tier-2/3 alias (19.2 MB)
    bool a_ok = (base + (size_t)N * D * sizeof(float) <= ws_size);

    int eGrid = (E + 255) / 256;
    int mlpGrid = (N + 63) / 64;
    int nbNode = (N + 255) / 256;
    int gatherGrid = 8 * ((nbNode + 1) / 2);
    int cvtGrid = (N * 4 + 255) / 256;

    if (csr_ok && a_ok) {
        // ---- CSR build ----
        hipMemsetAsync(deg, 0, (size_t)N * sizeof(int), stream);
        hist_kernel<<<eGrid, 256, 0, stream>>>(dst, deg, E);
        block_sums<<<nb, 256, 0, stream>>>(deg, bsums, N);
        scan_small<<<1, 64, 0, stream>>>(bsums, boff, rowptr + N, nb);
        scan_write<<<nb, 256, 0, stream>>>(deg, boff, rowptr, N);
        hipMemcpyAsync(cursor, rowptr, (size_t)N * sizeof(int),
                       hipMemcpyDeviceToDevice, stream);
        fill_edges<<<eGrid, 256, 0, stream>>>(src, dst, cursor, esrc, E);

        if (full_ok) {
            float4* agg4 = (float4*)agg;
            to_bf16_4g<<<cvtGrid, 256, 0, stream>>>((const float4*)feat, tab4, N);
            // layer 1: gather -> agg ; MLP -> tab4 (bf16 h1, reuses featb space)
            gather4<<<gatherGrid, 256, 0, stream>>>(tab4, rowptr, esrc, eps1, agg4, N);
            mlp96<<<mlpGrid, 256, 0, stream>>>(agg4, W1a, b1a, W1b, b1b, nullptr, tab4, N);
            // layer 2: gather -> agg ; MLP -> out fp32
            gather4<<<gatherGrid, 256, 0, stream>>>(tab4, rowptr, esrc, eps2, agg4, N);
            mlp96<<<mlpGrid, 256, 0, stream>>>(agg4, W2a, b2a, W2b, b2b, out, nullptr, N);
        } else {
            // tier 2: fused fp32 layers
            gin_layer_f32<<<mlpGrid, 256, 0, stream>>>(feat, rowptr, esrc, eps1,
                                                       W1a, b1a, W1b, b1b, A, N);
            gin_layer_f32<<<mlpGrid, 256, 0, stream>>>(A, rowptr, esrc, eps2,
                                                       W2a, b2a, W2b, b2b, out, N);
        }
    }
    // (ws_size has always been sufficient for csr+A in practice; if not, output
    // would be unpopulated — tiers above cover all observed configurations.)
}